// Round 12
// baseline (101.675 us; speedup 1.0000x reference)
//
#include <hip/hip_runtime.h>
#include <hip/hip_bf16.h>

typedef unsigned short u16;
typedef unsigned int u32;
typedef unsigned long long u64;
typedef short s16x8 __attribute__((ext_vector_type(8)));
typedef float f32x4 __attribute__((ext_vector_type(4)));
typedef float f32x16 __attribute__((ext_vector_type(16)));
typedef int i32x4 __attribute__((ext_vector_type(4)));

// fp32 -> bf16 round-to-nearest-even
static __device__ __forceinline__ u16 f2b(float f) {
    union { float f; unsigned u; } x; x.f = f;
    unsigned r = x.u + 0x7fffu + ((x.u >> 16) & 1u);
    return (u16)(r >> 16);
}

// pack two floats -> one u32 of 2 bf16 (low = a)
static __device__ __forceinline__ u32 pkbf2(float a, float b) {
    union { __hip_bfloat162 h; u32 u; } c;
    c.h = __float22bfloat162_rn(make_float2(a, b));
    return c.u;
}

static __device__ __forceinline__ f32x16 zero16() {
    f32x16 z;
#pragma unroll
    for (int i = 0; i < 16; i++) z[i] = 0.f;
    return z;
}

static __device__ __forceinline__ s16x8 mk8(u32 a, u32 b, u32 c, u32 d) {
    union { u32 u[4]; s16x8 v; } x;
    x.u[0] = a; x.u[1] = b; x.u[2] = c; x.u[3] = d;
    return x.v;
}

static __device__ __forceinline__ u32 sx32(u32 v) {
    return (u32)__shfl_xor((int)v, 32, 64);
}

// async global->LDS, 16B per lane; LDS dst = wave-uniform base + lane*16
static __device__ __forceinline__ void gll16(const u16* g, u16* l) {
    __builtin_amdgcn_global_load_lds(
        (const __attribute__((address_space(1))) u32*)g,
        (__attribute__((address_space(3))) u32*)l, 16, 0, 0);
}

// ---------------- fused pack/convert: one launch ----------------
// seg4 now emits bf16 AND-masks: one u32 per kv-pair (0xFFFF keep / 0x0000 drop)

__global__ __launch_bounds__(256)
void k_pack_all(const float* __restrict__ x, const int* __restrict__ mask,
                const float* __restrict__ Wq, const float* __restrict__ Wk,
                const float* __restrict__ Wv, const float* __restrict__ Wo,
                const float* __restrict__ bq, const float* __restrict__ bk,
                const float* __restrict__ bv, const float* __restrict__ bo,
                u16* __restrict__ xb, u16* __restrict__ WT, u16* __restrict__ WoT,
                float* __restrict__ bias, u32* __restrict__ mand) {
    int idx = blockIdx.x * 256 + threadIdx.x;
    if (idx < 524288) {
        int i = idx * 4;
        float4 v = *(const float4*)(x + i);
        ushort4 o;
        o.x = f2b(v.x); o.y = f2b(v.y); o.z = f2b(v.z); o.w = f2b(v.w);
        *(ushort4*)(xb + i) = o;
    } else if (idx < 1310720) {
        int t = idx - 524288;
        int z = t >> 18, r = t & 262143;
        const float* W = (z == 0) ? Wq : (z == 1) ? Wk : Wv;
        int n = r >> 9, d = r & 511;
        WT[t] = f2b(W[((n >> 6) * 512 + d) * 64 + (n & 63)]);
    } else if (idx < 1572864) {
        int r = idx - 1310720;
        int n = r >> 9, d = r & 511;
        WoT[r] = f2b(Wo[d * 512 + n]);
    } else if (idx < 1574912) {
        int i = idx - 1572864;
        float v;
        if (i < 512) v = bq[i];
        else if (i < 1024) v = bk[i - 512];
        else if (i < 1536) v = bv[i - 1024];
        else v = bo[i - 1536];
        bias[i] = v;
    } else {
        int i2 = idx - 1574912;
        const int4* p = (const int4*)(mask + (size_t)i2 * 32);
        u32* op = mand + (size_t)i2 * 16;
#pragma unroll
        for (int k = 0; k < 4; k++) {
            int4 v0 = p[2 * k], v1 = p[2 * k + 1];
            uint4 o;
            o.x = (v0.x ? 0u : 0xFFFFu) | (v0.y ? 0u : 0xFFFF0000u);
            o.y = (v0.z ? 0u : 0xFFFFu) | (v0.w ? 0u : 0xFFFF0000u);
            o.z = (v1.x ? 0u : 0xFFFFu) | (v1.y ? 0u : 0xFFFF0000u);
            o.w = (v1.z ? 0u : 0xFFFFu) | (v1.w ? 0u : 0xFFFF0000u);
            *(uint4*)(op + 4 * k) = o;
        }
    }
}

// ---------------- GEMM: C[4096,512] = A[4096,512] * BT[512,512]^T + bias ----
// BM = MF*32. z==0 (Q) epilogue folds the 1/8*log2(e) attention scale.
// z==2 (V projection) writes TRANSPOSED vt[b][he][s].

template<int MF, bool F32OUT>
__global__ __launch_bounds__(256)
void k_gemm(const u16* __restrict__ A, const u16* __restrict__ BTbase,
            const float* __restrict__ biasBase,
            u16* __restrict__ Cb, u16* __restrict__ Vt, float* __restrict__ Cf) {
    const int BM = MF * 32;
    const int nblk = blockIdx.x, mblk = blockIdx.y, z = blockIdx.z;
    const u16* BT = BTbase + (size_t)z * 262144;
    const float* bias = biasBase + z * 512;
    __shared__ __align__(16) u16 As[MF * 32 * 64];
    __shared__ __align__(16) u16 Bs[128 * 64];
    const int tid = threadIdx.x, lane = tid & 63, wv = tid >> 6;
    const int lr = lane & 15, lg = lane >> 4;
    const int wr = (wv >> 1) * (MF * 16), wc = (wv & 1) * 64;
    const u16* Ag = A + (size_t)(mblk * BM) * 512;
    const u16* Bg = BT + (size_t)(nblk * 128) * 512;

    f32x4 acc[MF][4];
#pragma unroll
    for (int i = 0; i < MF; i++)
#pragma unroll
        for (int j = 0; j < 4; j++) acc[i][j] = (f32x4){0.f, 0.f, 0.f, 0.f};

    for (int kt = 0; kt < 8; kt++) {
        __syncthreads();
#pragma unroll
        for (int i = 0; i < MF; i++) {
            int f = i * 256 + tid, r = f >> 3, c = f & 7;
            *(i32x4*)&As[r * 64 + ((c * 8) ^ ((r & 7) << 3))] =
                *(const i32x4*)(Ag + (size_t)r * 512 + kt * 64 + c * 8);
        }
#pragma unroll
        for (int i = 0; i < 4; i++) {
            int f = i * 256 + tid, r = f >> 3, c = f & 7;
            *(i32x4*)&Bs[r * 64 + ((c * 8) ^ ((r & 7) << 3))] =
                *(const i32x4*)(Bg + (size_t)r * 512 + kt * 64 + c * 8);
        }
        __syncthreads();
#pragma unroll
        for (int ks = 0; ks < 2; ks++) {
            s16x8 af[MF], bf[4];
#pragma unroll
            for (int mf = 0; mf < MF; mf++) {
                int r = wr + mf * 16 + lr;
                af[mf] = *(const s16x8*)&As[r * 64 + ((ks * 32 + lg * 8) ^ ((r & 7) << 3))];
            }
#pragma unroll
            for (int nf = 0; nf < 4; nf++) {
                int r = wc + nf * 16 + lr;
                bf[nf] = *(const s16x8*)&Bs[r * 64 + ((ks * 32 + lg * 8) ^ ((r & 7) << 3))];
            }
#pragma unroll
            for (int mf = 0; mf < MF; mf++)
#pragma unroll
                for (int nf = 0; nf < 4; nf++)
                    acc[mf][nf] = __builtin_amdgcn_mfma_f32_16x16x32_bf16(
                        af[mf], bf[nf], acc[mf][nf], 0, 0, 0);
        }
    }
    const float qsc = (!F32OUT && z == 0) ? 0.18033688011112042f : 1.0f;
#pragma unroll
    for (int nf = 0; nf < 4; nf++) {
        int col = nblk * 128 + wc + nf * 16 + lr;
        float bval = bias[col];
#pragma unroll
        for (int mf = 0; mf < MF; mf++) {
            int row0 = mblk * BM + wr + mf * 16 + lg * 4;
            if (F32OUT) {
#pragma unroll
                for (int r = 0; r < 4; r++)
                    Cf[(size_t)(row0 + r) * 512 + col] = acc[mf][nf][r] + bval;
            } else if (z == 2) {
                ushort4 o;
                o.x = f2b(acc[mf][nf][0] + bval);
                o.y = f2b(acc[mf][nf][1] + bval);
                o.z = f2b(acc[mf][nf][2] + bval);
                o.w = f2b(acc[mf][nf][3] + bval);
                *(ushort4*)(Vt + (size_t)(row0 >> 11) * 1048576 +
                            (size_t)col * 2048 + (row0 & 2047)) = o;
            } else {
#pragma unroll
                for (int r = 0; r < 4; r++)
                    Cb[(size_t)z * 2097152 + (size_t)(row0 + r) * 512 + col] =
                        f2b((acc[mf][nf][r] + bval) * qsc);
            }
        }
    }
}

// ---------------- flash attention v6: AND-mask + MFMA row-sum ----------------
// grid (qt=32, h=8, b=2) = 512 blocks, 512 threads = 8 warps, 2 blocks/CU.
// Fixed-max softmax (scores bounded); P packed to bf16 then masked with 8
// v_and_b32 from the precomputed AND-mask table; row-sum L = mfma(P, ones).
// Per tile: issue next tile's staging FIRST, QK^T -> exp/pack/AND -> exchange
// -> PV(+L), ONE barrier. Pointers strength-reduced.

__global__ __launch_bounds__(512, 4)
void k_attn(const u16* __restrict__ qkv, const u16* __restrict__ vt,
            const u32* __restrict__ mand, u16* __restrict__ oc) {
    const int qt = blockIdx.x, h = blockIdx.y, b = blockIdx.z;
    const u16* Qb = qkv + (size_t)b * 1048576 + h * 64;
    const u16* Kb = Qb + 2097152;
    const u16* VtH = vt + (size_t)b * 1048576 + (size_t)h * 131072;

    __shared__ __align__(16) u16 SMEM[32768];   // [buf 16384][quarter 4096: K 2048 | V 2048]
    __shared__ float Lbuf[8][32];

    const int tid = threadIdx.x;
    const int lane = tid & 63, w = tid >> 6;
    const int hi = lane >> 5, l31 = lane & 31;
    const int qg = w & 1, kvq = w >> 1;
    const int qrow = qt * 64 + qg * 32 + l31;

    // staging lane maps (pre-swizzled source, linear LDS dst)
    const int lr8 = lane >> 3, lc8 = (lane & 7) ^ lr8;                 // K: 8r x 8c(16B)
    const int vr16 = lane >> 2, vc4 = (lane & 3) ^ ((lane >> 3) & 3);  // V: 16r x 4c(16B)
    const int kvbase0 = kvq * 512;
    const int qoff = kvq * 4096;

    // Q fragments (B-operand), already scaled by 1/8*log2e
    s16x8 qf[4];
#pragma unroll
    for (int ks = 0; ks < 4; ks++)
        qf[ks] = *(const s16x8*)(Qb + (size_t)qrow * 512 + ks * 16 + hi * 8);

    // moving source pointers (strength-reduced)
    const u16* kptr = Kb + (size_t)(kvbase0 + qg * 16 + lr8) * 512 + lc8 * 8;
    const u16* vptr = VtH + (size_t)(qg * 32 + vr16) * 2048 + kvbase0 + vc4 * 8;
    const u32* mptr = mand + (size_t)(b * 2048 + qrow) * 1024 + kvq * 256 + 2 * hi;

    // prologue: stage tile 0 into buf 0
    gll16(kptr, &SMEM[qoff + (qg * 16) * 64]);
    gll16(kptr + 4096, &SMEM[qoff + (qg * 16 + 8) * 64]);
    gll16(vptr, &SMEM[qoff + 2048 + qg * 1024]);
    gll16(vptr + 32768, &SMEM[qoff + 2048 + qg * 1024 + 512]);
    uint2 mm0 = *(const uint2*)(mptr);
    uint2 mm1 = *(const uint2*)(mptr + 4);
    uint2 mm2 = *(const uint2*)(mptr + 8);
    uint2 mm3 = *(const uint2*)(mptr + 12);
    kptr += 16384; vptr += 32; mptr += 16;
    __syncthreads();

    f32x16 accO0 = zero16(), accO1 = zero16(), lacc = zero16();
    const s16x8 onesv = mk8(0x3F803F80u, 0x3F803F80u, 0x3F803F80u, 0x3F803F80u);
    const int kswz = (l31 & 7) << 3;
    const int vkey = (l31 >> 1) & 3;

    for (int t = 0; t < 16; t++) {
        const int bo = (t & 1) << 14;
        uint2 mn0, mn1, mn2, mn3;
        // ---- issue next tile's staging FIRST (drains at end-of-tile barrier) ----
        if (t < 15) {
            const int bn = bo ^ 16384;
            gll16(kptr, &SMEM[bn + qoff + (qg * 16) * 64]);
            gll16(kptr + 4096, &SMEM[bn + qoff + (qg * 16 + 8) * 64]);
            gll16(vptr, &SMEM[bn + qoff + 2048 + qg * 1024]);
            gll16(vptr + 32768, &SMEM[bn + qoff + 2048 + qg * 1024 + 512]);
            mn0 = *(const uint2*)(mptr);
            mn1 = *(const uint2*)(mptr + 4);
            mn2 = *(const uint2*)(mptr + 8);
            mn3 = *(const uint2*)(mptr + 12);
            kptr += 16384; vptr += 32; mptr += 16;
        }
        const u16* Kq = &SMEM[bo + qoff];
        const u16* Vq = &SMEM[bo + qoff + 2048];

        // ---- QK^T (swapped): S^T[kv32][q32], already log2-scaled ----
        f32x16 sa = zero16();
        __builtin_amdgcn_s_setprio(1);
#pragma unroll
        for (int ks = 0; ks < 4; ks++) {
            const int cb = ks * 16 + hi * 8;
            s16x8 kf = *(const s16x8*)&Kq[l31 * 64 + (cb ^ kswz)];
            sa = __builtin_amdgcn_mfma_f32_32x32x16_bf16(kf, qf[ks], sa, 0, 0, 0);
        }
        __builtin_amdgcn_s_setprio(0);

        // ---- p = exp2(s), pack to bf16 pairs, AND-mask ----
        u32 pk[8];
#pragma unroll
        for (int g = 0; g < 8; g++) {
            float a = __builtin_amdgcn_exp2f(sa[2 * g]);
            float b2 = __builtin_amdgcn_exp2f(sa[2 * g + 1]);
            pk[g] = pkbf2(a, b2);
        }
        pk[0] &= mm0.x; pk[1] &= mm0.y;
        pk[2] &= mm1.x; pk[3] &= mm1.y;
        pk[4] &= mm2.x; pk[5] &= mm2.y;
        pk[6] &= mm3.x; pk[7] &= mm3.y;

        // ---- cross-half exchange, build PV A-frags ----
        s16x8 pa[2];
        {
            u32 x0 = sx32(pk[0]), x1 = sx32(pk[1]), x2 = sx32(pk[2]), x3 = sx32(pk[3]);
            u32 x4 = sx32(pk[4]), x5 = sx32(pk[5]), x6 = sx32(pk[6]), x7 = sx32(pk[7]);
            pa[0] = mk8(hi ? x2 : pk[0], hi ? x3 : pk[1],
                        hi ? pk[2] : x0, hi ? pk[3] : x1);
            pa[1] = mk8(hi ? x6 : pk[4], hi ? x7 : pk[5],
                        hi ? pk[6] : x4, hi ? pk[7] : x5);
        }

        // ---- PV + row-sum L (MFMA with ones) ----
        __builtin_amdgcn_s_setprio(1);
#pragma unroll
        for (int ksg = 0; ksg < 2; ksg++) {
            const int off = ((ksg * 2 + hi) ^ vkey) << 3;
            s16x8 bv0 = *(const s16x8*)&Vq[l31 * 32 + off];
            s16x8 bv1 = *(const s16x8*)&Vq[(32 + l31) * 32 + off];
            accO0 = __builtin_amdgcn_mfma_f32_32x32x16_bf16(pa[ksg], bv0, accO0, 0, 0, 0);
            accO1 = __builtin_amdgcn_mfma_f32_32x32x16_bf16(pa[ksg], bv1, accO1, 0, 0, 0);
        }
        lacc = __builtin_amdgcn_mfma_f32_32x32x16_bf16(pa[0], onesv, lacc, 0, 0, 0);
        lacc = __builtin_amdgcn_mfma_f32_32x32x16_bf16(pa[1], onesv, lacc, 0, 0, 0);
        __builtin_amdgcn_s_setprio(0);

        // ---- single barrier: drains our async stage, syncs quarter pairs ----
        __syncthreads();
        if (t < 15) { mm0 = mn0; mm1 = mn1; mm2 = mn2; mm3 = mn3; }
    }

    // ---- publish per-warp row sums (lacc rows = q, all cols equal) ----
    if (l31 == 0) {
#pragma unroll
        for (int r = 0; r < 16; r++)
            Lbuf[w][(r & 3) + 8 * (r >> 2) + 4 * hi] = lacc[r];
    }

    // ---- 4-way merge across kv-quarters: plain sums ----
    float* Obuf = (float*)SMEM;                 // 8 warps x 2048 floats = 64KB
    const int lx = (lane & 7) * 4;
    const int obase = w * 2048 + lane * 32;
    __syncthreads();                            // ensure tile-loop LDS reads done
#pragma unroll
    for (int g = 0; g < 4; g++) {
        *(f32x4*)&Obuf[obase + ((4 * g) ^ lx)] =
            (f32x4){accO0[4 * g], accO0[4 * g + 1], accO0[4 * g + 2], accO0[4 * g + 3]};
        *(f32x4*)&Obuf[obase + ((16 + 4 * g) ^ lx)] =
            (f32x4){accO1[4 * g], accO1[4 * g + 1], accO1[4 * g + 2], accO1[4 * g + 3]};
    }
    __syncthreads();

    // combine: this warp handles qg2=w&1, r-quarter rq=w>>1
    const int qg2 = w & 1, rq = w >> 1;
    f32x4 v0[4], v1[4];
#pragma unroll
    for (int j = 0; j < 4; j++) {
        const int wp = qg2 + 2 * j;
        v0[j] = *(const f32x4*)&Obuf[wp * 2048 + lane * 32 + ((rq * 4) ^ lx)];
        v1[j] = *(const f32x4*)&Obuf[wp * 2048 + lane * 32 + ((16 + rq * 4) ^ lx)];
    }
#pragma unroll
    for (int k = 0; k < 4; k++) {
        const int q_k = k + 8 * rq + 4 * hi;
        float D = Lbuf[qg2][q_k] + Lbuf[qg2 + 2][q_k] +
                  Lbuf[qg2 + 4][q_k] + Lbuf[qg2 + 6][q_k];
        float inv = 1.0f / D;
        float o0 = (v0[0][k] + v0[1][k] + v0[2][k] + v0[3][k]) * inv;
        float o1 = (v1[0][k] + v1[1][k] + v1[2][k] + v1[3][k]) * inv;
        const size_t orow = ((size_t)b * 2048 + qt * 64 + qg2 * 32 + q_k) * 512 + h * 64;
        oc[orow + l31]      = f2b(o0);
        oc[orow + 32 + l31] = f2b(o1);
    }
}

// ---------------- launcher ----------------

extern "C" void kernel_launch(void* const* d_in, const int* in_sizes, int n_in,
                              void* d_out, int out_size, void* d_ws, size_t ws_size,
                              hipStream_t stream) {
    const float* x    = (const float*)d_in[0];
    const int*   mask = (const int*)d_in[1];
    const float* Wq   = (const float*)d_in[2];
    const float* bq   = (const float*)d_in[3];
    const float* Wk   = (const float*)d_in[4];
    const float* bk   = (const float*)d_in[5];
    const float* Wv   = (const float*)d_in[6];
    const float* bv   = (const float*)d_in[7];
    const float* Wo   = (const float*)d_in[8];
    const float* bo   = (const float*)d_in[9];

    u16* xb     = (u16*)d_ws;              // 2097152 bf16 (4 MB)
    u16* WT     = xb + 2097152;            // 1.5 MB
    u16* WoT    = WT + 786432;             // 0.5 MB
    u16* qkv    = WoT + 262144;            // Q,K: 8 MB
    u16* vtp    = qkv + 4194304;           // 4 MB (vt[b][he][s])
    u16* oc     = qkv + 6291456;           // 4 MB
    float* bias = (float*)(oc + 2097152);  // 8 KB
    u32* mand   = (u32*)(bias + 2048);     // 4194304 u32 = 16 MB AND-mask table

    k_pack_all<<<7176, 256, 0, stream>>>(x, mask, Wq, Wk, Wv, Wo, bq, bk, bv, bo,
                                         xb, WT, WoT, bias, mand);
    k_gemm<2, false><<<dim3(4, 64, 3), 256, 0, stream>>>(xb, WT, bias, qkv, vtp, nullptr);
    k_attn<<<dim3(32, 8, 2), 512, 0, stream>>>(qkv, vtp, mand, oc);
    k_gemm<2, true><<<dim3(4, 64, 1), 256, 0, stream>>>(oc, WoT, bias + 1536,
                                                        nullptr, nullptr, (float*)d_out);
}

// Round 13
// 80.037 us; speedup vs baseline: 1.2703x; 1.2703x over previous
//
#include <hip/hip_runtime.h>
#include <hip/hip_bf16.h>

typedef unsigned short u16;
typedef unsigned int u32;
typedef unsigned long long u64;
typedef short s16x8 __attribute__((ext_vector_type(8)));
typedef float f32x4 __attribute__((ext_vector_type(4)));
typedef float f32x16 __attribute__((ext_vector_type(16)));
typedef int i32x4 __attribute__((ext_vector_type(4)));

// fp32 -> bf16 round-to-nearest-even
static __device__ __forceinline__ u16 f2b(float f) {
    union { float f; unsigned u; } x; x.f = f;
    unsigned r = x.u + 0x7fffu + ((x.u >> 16) & 1u);
    return (u16)(r >> 16);
}

// pack two floats -> one u32 of 2 bf16 (low = a)
static __device__ __forceinline__ u32 pkbf2(float a, float b) {
    union { __hip_bfloat162 h; u32 u; } c;
    c.h = __float22bfloat162_rn(make_float2(a, b));
    return c.u;
}

static __device__ __forceinline__ f32x16 zero16() {
    f32x16 z;
#pragma unroll
    for (int i = 0; i < 16; i++) z[i] = 0.f;
    return z;
}

static __device__ __forceinline__ s16x8 mk8(u32 a, u32 b, u32 c, u32 d) {
    union { u32 u[4]; s16x8 v; } x;
    x.u[0] = a; x.u[1] = b; x.u[2] = c; x.u[3] = d;
    return x.v;
}

static __device__ __forceinline__ u32 sx32(u32 v) {
    return (u32)__shfl_xor((int)v, 32, 64);
}

// async global->LDS, 16B per lane; LDS dst = wave-uniform base + lane*16
static __device__ __forceinline__ void gll16(const u16* g, u16* l) {
    __builtin_amdgcn_global_load_lds(
        (const __attribute__((address_space(1))) u32*)g,
        (__attribute__((address_space(3))) u32*)l, 16, 0, 0);
}

// ---------------- fused pack/convert: one launch ----------------
// seg4: mask bits, mb[(b*2048+s)*64 + c32] bit j = mask[s][c32*32+j]

__global__ __launch_bounds__(256)
void k_pack_all(const float* __restrict__ x, const int* __restrict__ mask,
                const float* __restrict__ Wq, const float* __restrict__ Wk,
                const float* __restrict__ Wv, const float* __restrict__ Wo,
                const float* __restrict__ bq, const float* __restrict__ bk,
                const float* __restrict__ bv, const float* __restrict__ bo,
                u16* __restrict__ xb, u16* __restrict__ WT, u16* __restrict__ WoT,
                float* __restrict__ bias, u32* __restrict__ mb) {
    int idx = blockIdx.x * 256 + threadIdx.x;
    if (idx < 524288) {
        int i = idx * 4;
        float4 v = *(const float4*)(x + i);
        ushort4 o;
        o.x = f2b(v.x); o.y = f2b(v.y); o.z = f2b(v.z); o.w = f2b(v.w);
        *(ushort4*)(xb + i) = o;
    } else if (idx < 1310720) {
        int t = idx - 524288;
        int z = t >> 18, r = t & 262143;
        const float* W = (z == 0) ? Wq : (z == 1) ? Wk : Wv;
        int n = r >> 9, d = r & 511;
        WT[t] = f2b(W[((n >> 6) * 512 + d) * 64 + (n & 63)]);
    } else if (idx < 1572864) {
        int r = idx - 1310720;
        int n = r >> 9, d = r & 511;
        WoT[r] = f2b(Wo[d * 512 + n]);
    } else if (idx < 1574912) {
        int i = idx - 1572864;
        float v;
        if (i < 512) v = bq[i];
        else if (i < 1024) v = bk[i - 512];
        else if (i < 1536) v = bv[i - 1024];
        else v = bo[i - 1536];
        bias[i] = v;
    } else {
        int i2 = idx - 1574912;
        const int* p = mask + (size_t)i2 * 32;
        unsigned wv2 = 0;
#pragma unroll
        for (int j = 0; j < 32; j += 4) {
            int4 v = *(const int4*)(p + j);
            wv2 |= ((unsigned)(v.x & 1) << j) | ((unsigned)(v.y & 1) << (j + 1)) |
                   ((unsigned)(v.z & 1) << (j + 2)) | ((unsigned)(v.w & 1) << (j + 3));
        }
        mb[i2] = wv2;
    }
}

// ---------------- GEMM: C[4096,512] = A[4096,512] * BT[512,512]^T + bias ----
// BM = MF*32. z==0 (Q) epilogue folds the 1/8*log2(e) attention scale.
// z==2 (V projection) writes TRANSPOSED vt[b][he][s].

template<int MF, bool F32OUT>
__global__ __launch_bounds__(256)
void k_gemm(const u16* __restrict__ A, const u16* __restrict__ BTbase,
            const float* __restrict__ biasBase,
            u16* __restrict__ Cb, u16* __restrict__ Vt, float* __restrict__ Cf) {
    const int BM = MF * 32;
    const int nblk = blockIdx.x, mblk = blockIdx.y, z = blockIdx.z;
    const u16* BT = BTbase + (size_t)z * 262144;
    const float* bias = biasBase + z * 512;
    __shared__ __align__(16) u16 As[MF * 32 * 64];
    __shared__ __align__(16) u16 Bs[128 * 64];
    const int tid = threadIdx.x, lane = tid & 63, wv = tid >> 6;
    const int lr = lane & 15, lg = lane >> 4;
    const int wr = (wv >> 1) * (MF * 16), wc = (wv & 1) * 64;
    const u16* Ag = A + (size_t)(mblk * BM) * 512;
    const u16* Bg = BT + (size_t)(nblk * 128) * 512;

    f32x4 acc[MF][4];
#pragma unroll
    for (int i = 0; i < MF; i++)
#pragma unroll
        for (int j = 0; j < 4; j++) acc[i][j] = (f32x4){0.f, 0.f, 0.f, 0.f};

    for (int kt = 0; kt < 8; kt++) {
        __syncthreads();
#pragma unroll
        for (int i = 0; i < MF; i++) {
            int f = i * 256 + tid, r = f >> 3, c = f & 7;
            *(i32x4*)&As[r * 64 + ((c * 8) ^ ((r & 7) << 3))] =
                *(const i32x4*)(Ag + (size_t)r * 512 + kt * 64 + c * 8);
        }
#pragma unroll
        for (int i = 0; i < 4; i++) {
            int f = i * 256 + tid, r = f >> 3, c = f & 7;
            *(i32x4*)&Bs[r * 64 + ((c * 8) ^ ((r & 7) << 3))] =
                *(const i32x4*)(Bg + (size_t)r * 512 + kt * 64 + c * 8);
        }
        __syncthreads();
#pragma unroll
        for (int ks = 0; ks < 2; ks++) {
            s16x8 af[MF], bf[4];
#pragma unroll
            for (int mf = 0; mf < MF; mf++) {
                int r = wr + mf * 16 + lr;
                af[mf] = *(const s16x8*)&As[r * 64 + ((ks * 32 + lg * 8) ^ ((r & 7) << 3))];
            }
#pragma unroll
            for (int nf = 0; nf < 4; nf++) {
                int r = wc + nf * 16 + lr;
                bf[nf] = *(const s16x8*)&Bs[r * 64 + ((ks * 32 + lg * 8) ^ ((r & 7) << 3))];
            }
#pragma unroll
            for (int mf = 0; mf < MF; mf++)
#pragma unroll
                for (int nf = 0; nf < 4; nf++)
                    acc[mf][nf] = __builtin_amdgcn_mfma_f32_16x16x32_bf16(
                        af[mf], bf[nf], acc[mf][nf], 0, 0, 0);
        }
    }
    const float qsc = (!F32OUT && z == 0) ? 0.18033688011112042f : 1.0f;
#pragma unroll
    for (int nf = 0; nf < 4; nf++) {
        int col = nblk * 128 + wc + nf * 16 + lr;
        float bval = bias[col];
#pragma unroll
        for (int mf = 0; mf < MF; mf++) {
            int row0 = mblk * BM + wr + mf * 16 + lg * 4;
            if (F32OUT) {
#pragma unroll
                for (int r = 0; r < 4; r++)
                    Cf[(size_t)(row0 + r) * 512 + col] = acc[mf][nf][r] + bval;
            } else if (z == 2) {
                ushort4 o;
                o.x = f2b(acc[mf][nf][0] + bval);
                o.y = f2b(acc[mf][nf][1] + bval);
                o.z = f2b(acc[mf][nf][2] + bval);
                o.w = f2b(acc[mf][nf][3] + bval);
                *(ushort4*)(Vt + (size_t)(row0 >> 11) * 1048576 +
                            (size_t)col * 2048 + (row0 & 2047)) = o;
            } else {
#pragma unroll
                for (int r = 0; r < 4; r++)
                    Cb[(size_t)z * 2097152 + (size_t)(row0 + r) * 512 + col] =
                        f2b((acc[mf][nf][r] + bval) * qsc);
            }
        }
    }
}

// ---------------- flash attention v7: barrier-free wave-private pipeline -----
// grid (qt=32, h=8, b=2) = 512 blocks, 256 threads = 4 warps, 2 blocks/CU.
// Warp w = kv-quarter, handles BOTH q-groups (64 q rows): K/V fragments reused
// across the two q-group MFMAs. Staging is wave-private (K 4KB + V^T 4KB,
// double-buffered) via global_load_lds issued one tile ahead; synchronization
// is a counted s_waitcnt vmcnt(10) — NO __syncthreads in the loop. Fixed-max
// softmax (scores bounded; Q pre-scaled by 1/8*log2e). One barrier at merge.

__global__ __launch_bounds__(256, 2)
void k_attn(const u16* __restrict__ qkv, const u16* __restrict__ vt,
            const u32* __restrict__ mb, u16* __restrict__ oc) {
    const int qt = blockIdx.x, h = blockIdx.y, b = blockIdx.z;
    const u16* Qb = qkv + (size_t)b * 1048576 + h * 64;
    const u16* Kb = Qb + 2097152;
    const u16* VtH = vt + (size_t)b * 1048576 + (size_t)h * 131072;

    __shared__ __align__(16) u16 SMEM[32768];   // 4 warps x 8192: [2 buf][K 2048 | V 2048]
    __shared__ float Lbuf[4][64];

    const int tid = threadIdx.x;
    const int lane = tid & 63, w = tid >> 6;    // w = kv-quarter
    const int hi = lane >> 5, l31 = lane & 31;
    const int qrow = qt * 64 + l31;             // qg0; qg1 = +32

    // Q fragments (B-operand) for both q-groups, pre-scaled by 1/8*log2e
    s16x8 qfl[4], qfh[4];
#pragma unroll
    for (int ks = 0; ks < 4; ks++) {
        qfl[ks] = *(const s16x8*)(Qb + (size_t)qrow * 512 + ks * 16 + hi * 8);
        qfh[ks] = *(const s16x8*)(Qb + (size_t)(qrow + 32) * 512 + ks * 16 + hi * 8);
    }

    // staging lane maps (pre-swizzled source, linear LDS dst)
    const int lr8 = lane >> 3, lc8 = (lane & 7) ^ lr8;                 // K: 8r x 8c(16B)
    const int vr16 = lane >> 2, vc4 = (lane & 3) ^ ((lane >> 3) & 3);  // V: 16r x 4c(16B)
    const int kv0 = w * 512;

    const u16* kptr = Kb + (size_t)(kv0 + lr8) * 512 + lc8 * 8;
    const u16* vptr = VtH + (size_t)vr16 * 2048 + kv0 + vc4 * 8;
    const u32* mbl = mb + (size_t)(b * 2048 + qrow) * 64 + w * 16;
    const u32* mbh = mbl + 2048;   // +32 rows * 64 words

    u16* wbase = &SMEM[w * 8192];

    // prologue: tile 0 into buf 0 (8 gll + 2 mask loads = 10 vmem)
#pragma unroll
    for (int i = 0; i < 4; i++) {
        gll16(kptr + (size_t)(i * 8) * 512, wbase + i * 512);
        gll16(vptr + (size_t)(i * 16) * 2048, wbase + 2048 + i * 512);
    }
    u32 ml = mbl[0], mh = mbh[0];

    f32x16 aL0 = zero16(), aL1 = zero16(), aH0 = zero16(), aH1 = zero16();
    f32x4 lvl = (f32x4){0.f, 0.f, 0.f, 0.f}, lvh = (f32x4){0.f, 0.f, 0.f, 0.f};
    const int kswz = (l31 & 7) << 3;
    const int vkey = (l31 >> 1) & 3;

    for (int t = 0; t < 16; t++) {
        const u16* Kq = wbase + (t & 1) * 4096;
        const u16* Vq = Kq + 2048;
        u32 mnl = 0, mnh = 0;
        if (t < 15) {
            // issue tile t+1 staging (8 gll + 2 mask = 10 vmem), then counted wait:
            // vmcnt(10) leaves exactly the new batch in flight -> tile t landed.
            const u16* kp = kptr + (size_t)((t + 1) * 32) * 512;
            const u16* vp = vptr + (t + 1) * 32;
            u16* db = wbase + (((t + 1) & 1) << 12);
#pragma unroll
            for (int i = 0; i < 4; i++) {
                gll16(kp + (size_t)(i * 8) * 512, db + i * 512);
                gll16(vp + (size_t)(i * 16) * 2048, db + 2048 + i * 512);
            }
            mnl = mbl[t + 1];
            mnh = mbh[t + 1];
            asm volatile("s_waitcnt vmcnt(10)" ::: "memory");
        } else {
            asm volatile("s_waitcnt vmcnt(0)" ::: "memory");
        }
        __builtin_amdgcn_sched_barrier(0);

        // ---- QK^T (swapped) for both q-groups; kf read once, used twice ----
        f32x16 sl = zero16(), sh = zero16();
        __builtin_amdgcn_s_setprio(1);
#pragma unroll
        for (int ks = 0; ks < 4; ks++) {
            s16x8 kf = *(const s16x8*)&Kq[l31 * 64 + ((ks * 16 + hi * 8) ^ kswz)];
            sl = __builtin_amdgcn_mfma_f32_32x32x16_bf16(kf, qfl[ks], sl, 0, 0, 0);
            sh = __builtin_amdgcn_mfma_f32_32x32x16_bf16(kf, qfh[ks], sh, 0, 0, 0);
        }
        __builtin_amdgcn_s_setprio(0);

        // ---- fixed-max softmax + pack + half-exchange, q-group 0 ----
        s16x8 pal0, pal1, pah0, pah1;
        {
            const u32 mw = ml >> (hi * 4);
            u32 pk[8];
#pragma unroll
            for (int g = 0; g < 8; g++) {
                const int p0 = ((2 * g) & 3) + 8 * (g >> 1);
                float a = ((mw >> p0) & 1u) ? 0.f : __builtin_amdgcn_exp2f(sl[2 * g]);
                float b2 = ((mw >> (p0 + 1)) & 1u) ? 0.f : __builtin_amdgcn_exp2f(sl[2 * g + 1]);
                lvl[(2 * g) & 3] += a;
                lvl[(2 * g + 1) & 3] += b2;
                pk[g] = pkbf2(a, b2);
            }
            u32 xa = sx32(hi ? pk[0] : pk[2]);
            u32 xb = sx32(hi ? pk[1] : pk[3]);
            u32 xc = sx32(hi ? pk[4] : pk[6]);
            u32 xd = sx32(hi ? pk[5] : pk[7]);
            pal0 = hi ? mk8(xa, xb, pk[2], pk[3]) : mk8(pk[0], pk[1], xa, xb);
            pal1 = hi ? mk8(xc, xd, pk[6], pk[7]) : mk8(pk[4], pk[5], xc, xd);
        }
        // ---- q-group 1 ----
        {
            const u32 mw = mh >> (hi * 4);
            u32 pk[8];
#pragma unroll
            for (int g = 0; g < 8; g++) {
                const int p0 = ((2 * g) & 3) + 8 * (g >> 1);
                float a = ((mw >> p0) & 1u) ? 0.f : __builtin_amdgcn_exp2f(sh[2 * g]);
                float b2 = ((mw >> (p0 + 1)) & 1u) ? 0.f : __builtin_amdgcn_exp2f(sh[2 * g + 1]);
                lvh[(2 * g) & 3] += a;
                lvh[(2 * g + 1) & 3] += b2;
                pk[g] = pkbf2(a, b2);
            }
            u32 xa = sx32(hi ? pk[0] : pk[2]);
            u32 xb = sx32(hi ? pk[1] : pk[3]);
            u32 xc = sx32(hi ? pk[4] : pk[6]);
            u32 xd = sx32(hi ? pk[5] : pk[7]);
            pah0 = hi ? mk8(xa, xb, pk[2], pk[3]) : mk8(pk[0], pk[1], xa, xb);
            pah1 = hi ? mk8(xc, xd, pk[6], pk[7]) : mk8(pk[4], pk[5], xc, xd);
        }

        // ---- PV: bv read once, used for both q-groups ----
        __builtin_amdgcn_s_setprio(1);
#pragma unroll
        for (int ksg = 0; ksg < 2; ksg++) {
            const int off = ((ksg * 2 + hi) ^ vkey) << 3;
            s16x8 bv0 = *(const s16x8*)&Vq[l31 * 32 + off];
            s16x8 bv1 = *(const s16x8*)&Vq[(32 + l31) * 32 + off];
            s16x8 pl = ksg ? pal1 : pal0;
            s16x8 ph = ksg ? pah1 : pah0;
            aL0 = __builtin_amdgcn_mfma_f32_32x32x16_bf16(pl, bv0, aL0, 0, 0, 0);
            aL1 = __builtin_amdgcn_mfma_f32_32x32x16_bf16(pl, bv1, aL1, 0, 0, 0);
            aH0 = __builtin_amdgcn_mfma_f32_32x32x16_bf16(ph, bv0, aH0, 0, 0, 0);
            aH1 = __builtin_amdgcn_mfma_f32_32x32x16_bf16(ph, bv1, aH1, 0, 0, 0);
        }
        __builtin_amdgcn_s_setprio(0);

        ml = mnl; mh = mnh;
    }

    // ---- per-q L across halves (one shuffle per q-group) ----
    float Lsl = (lvl[0] + lvl[1]) + (lvl[2] + lvl[3]);
    Lsl += __shfl_xor(Lsl, 32, 64);
    float Lsh = (lvh[0] + lvh[1]) + (lvh[2] + lvh[3]);
    Lsh += __shfl_xor(Lsh, 32, 64);
    if (lane < 32) { Lbuf[w][l31] = Lsl; Lbuf[w][32 + l31] = Lsh; }

    // ---- write partial O to own LDS region (overlays own staging) ----
    float* Obuf = (float*)SMEM;                 // warp w region: [w*4096, +4096) floats
    const int lx = (lane & 7) * 4;
    const int ob = w * 4096 + lane * 32;
#pragma unroll
    for (int g = 0; g < 4; g++) {
        *(f32x4*)&Obuf[ob + ((4 * g) ^ lx)] =
            (f32x4){aL0[4 * g], aL0[4 * g + 1], aL0[4 * g + 2], aL0[4 * g + 3]};
        *(f32x4*)&Obuf[ob + ((16 + 4 * g) ^ lx)] =
            (f32x4){aL1[4 * g], aL1[4 * g + 1], aL1[4 * g + 2], aL1[4 * g + 3]};
        *(f32x4*)&Obuf[ob + 2048 + ((4 * g) ^ lx)] =
            (f32x4){aH0[4 * g], aH0[4 * g + 1], aH0[4 * g + 2], aH0[4 * g + 3]};
        *(f32x4*)&Obuf[ob + 2048 + ((16 + 4 * g) ^ lx)] =
            (f32x4){aH1[4 * g], aH1[4 * g + 1], aH1[4 * g + 2], aH1[4 * g + 3]};
    }
    __syncthreads();                            // the ONLY workgroup barrier

    // ---- combine 4 kv-quarter partials: warp handles (qg2 = w&1, eh = w>>1) ----
    const int qg2 = w & 1, eh = w >> 1;
    const int rb2 = qg2 * 2048 + lane * 32;
#pragma unroll
    for (int g = 0; g < 4; g++) {
        const int off = (16 * eh + 4 * g) ^ lx;
        f32x4 s0 = *(const f32x4*)&Obuf[rb2 + off];
        f32x4 s1 = *(const f32x4*)&Obuf[4096 + rb2 + off];
        f32x4 s2 = *(const f32x4*)&Obuf[8192 + rb2 + off];
        f32x4 s3 = *(const f32x4*)&Obuf[12288 + rb2 + off];
        f32x4 sum = (s0 + s1) + (s2 + s3);
#pragma unroll
        for (int j = 0; j < 4; j++) {
            const int q = j + 4 * hi + 8 * g;
            float D = Lbuf[0][qg2 * 32 + q] + Lbuf[1][qg2 * 32 + q] +
                      Lbuf[2][qg2 * 32 + q] + Lbuf[3][qg2 * 32 + q];
            const size_t orow = ((size_t)b * 2048 + qt * 64 + qg2 * 32 + q) * 512 +
                                h * 64 + eh * 32;
            oc[orow + l31] = f2b(sum[j] / D);
        }
    }
}

// ---------------- launcher ----------------

extern "C" void kernel_launch(void* const* d_in, const int* in_sizes, int n_in,
                              void* d_out, int out_size, void* d_ws, size_t ws_size,
                              hipStream_t stream) {
    const float* x    = (const float*)d_in[0];
    const int*   mask = (const int*)d_in[1];
    const float* Wq   = (const float*)d_in[2];
    const float* bq   = (const float*)d_in[3];
    const float* Wk   = (const float*)d_in[4];
    const float* bk   = (const float*)d_in[5];
    const float* Wv   = (const float*)d_in[6];
    const float* bv   = (const float*)d_in[7];
    const float* Wo   = (const float*)d_in[8];
    const float* bo   = (const float*)d_in[9];

    u16* xb     = (u16*)d_ws;              // 2097152 bf16
    u16* WT     = xb + 2097152;            // 3*262144
    u16* WoT    = WT + 786432;             // 262144
    u16* qkv    = WoT + 262144;            // Q,K: 2*2097152
    u16* vtp    = qkv + 4194304;           // 2097152 (vt[b][he][s])
    u16* oc     = qkv + 6291456;           // 2097152
    float* bias = (float*)(oc + 2097152);  // 2048 floats
    u32* mbits  = (u32*)(bias + 2048);     // 262144 words (1 MB)

    k_pack_all<<<7176, 256, 0, stream>>>(x, mask, Wq, Wk, Wv, Wo, bq, bk, bv, bo,
                                         xb, WT, WoT, bias, mbits);
    k_gemm<2, false><<<dim3(4, 64, 3), 256, 0, stream>>>(xb, WT, bias, qkv, vtp, nullptr);
    k_attn<<<dim3(32, 8, 2), 256, 0, stream>>>(qkv, vtp, mbits, oc);
    k_gemm<2, true><<<dim3(4, 64, 1), 256, 0, stream>>>(oc, WoT, bias + 1536,
                                                        nullptr, nullptr, (float*)d_out);
}